// Round 9
// baseline (10023.426 us; speedup 1.0000x reference)
//
#include <hip/hip_runtime.h>

typedef float v2f __attribute__((ext_vector_type(2)));
typedef unsigned long long ull;

// Problem dims
#define B_Q 128
#define T_Q 1024
#define I_Q 256
#define H_Q 512

// Partition (r9): 4 PAIRS of groups; each WG serves BOTH groups of its pair
// with 8 batches each (half hf). 64 slices x 2 halves x 4 pairs = 512 WGs x
// 256 thr (residency law: launch_bounds arg 2 -> 2 WGs/CU -> exactly 512
// slots, fully resident).
// WHY (r8 post-mortem): co-resident WGs are timing-identical -> phase-lock ->
// sync+reload latency (~5.7us/step) never overlaps compute. The A/B in-WG
// interleave hides A's publish->flag->poll->reload under B's compute and vice
// versa -- anti-phase by construction, within each wave.
// SYNC: per-WG flag STORES + parallel poll (r6/r7 proven, no RMW). ONE spin
// per step (flag set after BOTH halves' publish; consumers check a full
// compute-phase later -> always ready).
// MAPPING: pair p on XCDs {2p,2p+1} (hf = xcd&1) -> FETCH locality kept (r8:
// 1.59e6 -> 4.1e5 KB, proven). Correctness is mapping-independent.
// SQ_LDS_BANK_CONFLICT ~2e8 is the inherent wave64 2-lane/bank aliasing
// (constant across ALL layouts r0-r8; m136: timing-free). Not a target.
#define BH     8                         // batches per half
#define JW     8
#define NWG    512
#define NTHR   256
#define C1     (B_Q * 4 * H_Q)           // copy-1 offset in out (262144 floats)

// LDS: 16 rows (A=0..7, B=8..15) x 64 chunks x (8 floats + 2 pad) + 2 transpose bufs
#define CH_STR  10
#define ROW_STR 640                      // 64*10, multiple of 32 -> XOR-row bank-invariant
#define HT_FLOATS (16 * ROW_STR)         // 10240
#define LDS_FLOATS (HT_FLOATS + 2 * 72)
#define LDS_BYTES  (LDS_FLOATS * 4)      // 41536 B

// ---- cross-lane partner fetch, compile-time ctrl (DPP for 1,2,8; swizzle 4,16)
template<int M>
__device__ __forceinline__ float partner(float t) {
    if constexpr (M == 16)
        return __int_as_float(__builtin_amdgcn_ds_swizzle(__float_as_int(t), 0x401F));
    else if constexpr (M == 8)
        return __int_as_float(__builtin_amdgcn_update_dpp(0, __float_as_int(t), 0x128, 0xF, 0xF, true)); // row_ror:8 = xor8
    else if constexpr (M == 4)
        return __int_as_float(__builtin_amdgcn_ds_swizzle(__float_as_int(t), 0x101F));
    else if constexpr (M == 2)
        return __int_as_float(__builtin_amdgcn_update_dpp(0, __float_as_int(t), 0x4E, 0xF, 0xF, true));  // quad_perm [2,3,0,1]
    else
        return __int_as_float(__builtin_amdgcn_update_dpp(0, __float_as_int(t), 0xB1, 0xF, 0xF, true));  // quad_perm [1,0,3,2]
}

// ---- phase-1 butterfly (linear slots, 8 batches): fold ^16 and ^8 symmetric
// (both partners hold the same batch set), then reduce-scatter ^4..^1 with
// keep/send selects. After: EVERY lane kg has v[0] = sum for batch (kg & 7).
template<int M, int N>
__device__ __forceinline__ void bstage(float* v, bool hi) {
    #pragma unroll
    for (int i = 0; i < N / 2; ++i) {
        float keep = hi ? v[i + N / 2] : v[i];
        float send = hi ? v[i]         : v[i + N / 2];
        v[i] = keep + partner<M>(send);
    }
}
__device__ __forceinline__ void bflychunk8(float* v, int kg) {
    #pragma unroll
    for (int i = 0; i < 8; ++i) v[i] += partner<16>(v[i]);
    #pragma unroll
    for (int i = 0; i < 8; ++i) v[i] += partner<8>(v[i]);
    bstage<4, 8>(v, (kg & 4) != 0);
    bstage<2, 4>(v, (kg & 2) != 0);
    bstage<1, 2>(v, (kg & 1) != 0);
}

// ---- phase-2 butterfly (XOR slots, select-free): slot i of lane kg holds
// batch (i ^ (kg&7)); every stage v[i] += partner<M>(v[i+M]); ^8 and ^16
// folds are symmetric. After: v[0] = sum for batch (kg & 7) on every lane.
__device__ __forceinline__ void bfly8x(float* v) {
    #pragma unroll
    for (int i = 0; i < 4; ++i) v[i] += partner<4>(v[i + 4]);
    v[0] += partner<2>(v[2]);
    v[1] += partner<2>(v[3]);
    v[0] += partner<1>(v[1]);
    v[0] += partner<8>(v[0]);
    v[0] += partner<16>(v[0]);
}

// fast gates: v_exp_f32 (base-2) + v_rcp_f32; saturating tails exact
__device__ __forceinline__ float fsig(float x) {
    return __builtin_amdgcn_rcpf(1.f + __builtin_amdgcn_exp2f(-1.44269504088896f * x));
}
__device__ __forceinline__ float ftanh(float x) {
    return 1.f - 2.f * __builtin_amdgcn_rcpf(1.f + __builtin_amdgcn_exp2f(2.88539008177793f * x));
}

// x partials for one half (8 batches, linear slots -> coalesced loads)
__device__ __forceinline__ void xpart(const float* xt, size_t xstr_b,
                                      const v2f (*wi)[4], int kg, float* ox) {
    float pr[BH], pz[BH], pn[BH];
    #pragma unroll
    for (int i = 0; i < BH; ++i) {
        const float* xp = xt + (size_t)i * xstr_b;
        float4 xa4 = *(const float4*)(xp);
        float4 xb4 = *(const float4*)(xp + 4);
        v2f x0 = (v2f){xa4.x, xa4.y}, x1 = (v2f){xa4.z, xa4.w};
        v2f x2 = (v2f){xb4.x, xb4.y}, x3 = (v2f){xb4.z, xb4.w};
        v2f sr = x0 * wi[0][0] + x1 * wi[0][1] + x2 * wi[0][2] + x3 * wi[0][3];
        v2f sz = x0 * wi[1][0] + x1 * wi[1][1] + x2 * wi[1][2] + x3 * wi[1][3];
        v2f sn = x0 * wi[2][0] + x1 * wi[2][1] + x2 * wi[2][2] + x3 * wi[2][3];
        pr[i] = sr.x + sr.y; pz[i] = sz.x + sz.y; pn[i] = sn.x + sn.y;
    }
    bflychunk8(pr, kg); bflychunk8(pz, kg); bflychunk8(pn, kg);
    ox[0] = pr[0]; ox[1] = pz[0]; ox[2] = pn[0];
}

// h partials for one half (Hrow0 = Ht row base for this half)
__device__ __forceinline__ void hpart(const float* Hrow0, const v2f (*wh)[8],
                                      int kg, int c7, float* oh) {
    float pr[BH], pz[BH], pn[BH];
    #pragma unroll
    for (int i = 0; i < BH; ++i) {
        const float* hp = Hrow0 + (i ^ c7) * ROW_STR + CH_STR * kg;
        v2f a0 = *(const v2f*)(hp);
        v2f a1 = *(const v2f*)(hp + 2);
        v2f a2 = *(const v2f*)(hp + 4);
        v2f a3 = *(const v2f*)(hp + 6);
        const float* hq = hp + 32 * CH_STR;   // chunk kg+32: k = 256+8kg
        v2f c0 = *(const v2f*)(hq);
        v2f c1 = *(const v2f*)(hq + 2);
        v2f c2 = *(const v2f*)(hq + 4);
        v2f c3 = *(const v2f*)(hq + 6);
        v2f sr = a0 * wh[0][0] + a1 * wh[0][1] + a2 * wh[0][2] + a3 * wh[0][3]
               + c0 * wh[0][4] + c1 * wh[0][5] + c2 * wh[0][6] + c3 * wh[0][7];
        v2f sz = a0 * wh[1][0] + a1 * wh[1][1] + a2 * wh[1][2] + a3 * wh[1][3]
               + c0 * wh[1][4] + c1 * wh[1][5] + c2 * wh[1][6] + c3 * wh[1][7];
        v2f sn = a0 * wh[2][0] + a1 * wh[2][1] + a2 * wh[2][2] + a3 * wh[2][3]
               + c0 * wh[2][4] + c1 * wh[2][5] + c2 * wh[2][6] + c3 * wh[2][7];
        pr[i] = sr.x + sr.y; pz[i] = sz.x + sz.y; pn[i] = sn.x + sn.y;
    }
    bfly8x(pr); bfly8x(pz); bfly8x(pn);
    oh[0] = pr[0]; oh[1] = pz[0]; oh[2] = pn[0];
}

// 8 rows x 512 floats (4096 floats = 2048 ull), 256 thr x 8 each
__device__ __forceinline__ void stageHalf(const ull* src, float* HtRows, int tid) {
    #pragma unroll
    for (int i = 0; i < BH; ++i) {
        int q = tid + i * NTHR;            // 0..2047
        int b = q >> 8, qr = q & 255;
        ull v = __hip_atomic_load(src + q, __ATOMIC_RELAXED,
                                  __HIP_MEMORY_SCOPE_AGENT);
        *(ull*)(HtRows + b * ROW_STR + (qr >> 2) * CH_STR + ((qr & 3) << 1)) = v;
    }
}

extern "C" __global__ void __launch_bounds__(NTHR, 2)
__attribute__((amdgpu_num_vgpr(128)))   // fail-safe: spill beats residency loss
gru_scan_kernel(const float* __restrict__ x,
                const float* __restrict__ h0,
                const float* __restrict__ Wih,
                const float* __restrict__ bih,
                const float* __restrict__ Whh,
                const float* __restrict__ bhh,
                float* __restrict__ out,
                int* __restrict__ flags)   // d_ws: NWG per-WG flags, memset-0 by host
{
    extern __shared__ float lds[];
    float* Ht    = lds;                 // rows 0..7 = A, 8..15 = B
    float* tbufA = lds + HT_FLOATS;     // [8][9]
    float* tbufB = tbufA + 72;          // [8][9]

    const int wg  = blockIdx.x;
    const int xcd = wg & 7;               // XCD id (round-robin dispatch)
    const int r   = wg >> 3;              // slot within XCD 0..63
    const int p   = xcd >> 1;             // pair 0..3  (groups 2p, 2p+1)
    const int hf  = xcd & 1;              // half: batches hf*8..hf*8+7
    const int s   = r;                    // slice 0..63
    const int gA  = 2 * p, gB = 2 * p + 1;
    const int tid = threadIdx.x;
    const int j   = tid >> 5;             // 0..7 local col
    const int kg  = tid & 31;             // 0..31 k-group
    const int jg  = s * JW + j;           // global h-col
    const int c7  = kg & 7;               // b_own within half

    // Per-group hbuf scratch in each group's OWN copy-1 region (occupancy-safe;
    // fully overwritten by valid outputs in the epilogue, after the pair-done spin).
    float* hbufA = out + C1 + (size_t)gA * (16 * 4 * H_Q);  // 2 parity x [16][H_Q]
    float* hbufB = out + C1 + (size_t)gB * (16 * 4 * H_Q);
    int*   pflags = flags + (p * 2 + hf) * 64;   // my half's 64 per-slice flags

    // ---- W slices (batch-independent -> shared by A and B)
    v2f wh[3][8];   // hh: k in [8kg,8kg+8) U [256+8kg, 256+8kg+8)
    v2f wi[3][4];   // ih: k in [8kg,8kg+8)
    #pragma unroll
    for (int gt = 0; gt < 3; ++gt) {
        const float* wr = Whh + (size_t)(gt * H_Q + jg) * H_Q + 8 * kg;
        float4 t0 = *(const float4*)(wr);
        float4 t1 = *(const float4*)(wr + 4);
        float4 t2 = *(const float4*)(wr + 256);
        float4 t3 = *(const float4*)(wr + 260);
        wh[gt][0] = (v2f){t0.x, t0.y}; wh[gt][1] = (v2f){t0.z, t0.w};
        wh[gt][2] = (v2f){t1.x, t1.y}; wh[gt][3] = (v2f){t1.z, t1.w};
        wh[gt][4] = (v2f){t2.x, t2.y}; wh[gt][5] = (v2f){t2.z, t2.w};
        wh[gt][6] = (v2f){t3.x, t3.y}; wh[gt][7] = (v2f){t3.z, t3.w};
        const float* wx = Wih + (size_t)(gt * H_Q + jg) * I_Q + 8 * kg;
        float4 u0 = *(const float4*)(wx);
        float4 u1 = *(const float4*)(wx + 4);
        wi[gt][0] = (v2f){u0.x, u0.y}; wi[gt][1] = (v2f){u0.z, u0.w};
        wi[gt][2] = (v2f){u1.x, u1.y}; wi[gt][3] = (v2f){u1.z, u1.w};
    }

    const float br = bih[jg]           + bhh[jg];
    const float bz = bih[H_Q + jg]     + bhh[H_Q + jg];
    const float bin = bih[2 * H_Q + jg], bhn = bhh[2 * H_Q + jg];

    const size_t xstr_b = (size_t)T_Q * I_Q;
    const float* xbaseA = x + (size_t)(gA * 16 + hf * BH) * xstr_b + 8 * kg;
    const float* xbaseB = x + (size_t)(gB * 16 + hf * BH) * xstr_b + 8 * kg;

    float lrA = 0, lzA = 0, lnA = 0, lhA = 0;
    float lrB = 0, lzB = 0, lnB = 0, lhB = 0;

    for (int t = 1; t <= T_Q; ++t) {
        // ======== half A ========
        float oxA[3];
        xpart(xbaseA + (size_t)(t - 1) * I_Q, xstr_b, wi, kg, oxA);

        // ONE spin per step: my half's 64 slices published t-1 (flags are set
        // after BOTH halves stored at t-1, so B's reload below needs no spin).
        if (t == 1) {
            stageHalf((const ull*)(h0 + (size_t)(gA * 16 + hf * BH) * H_Q), Ht, tid);
        } else {
            if (tid < 64) {
                int cnt = 0;
                while (__hip_atomic_load(pflags + tid, __ATOMIC_RELAXED,
                                         __HIP_MEMORY_SCOPE_AGENT) < t - 1) {
                    __builtin_amdgcn_s_sleep(1);
                    if (++cnt > 100000000) break;   // hang guard
                }
            }
            __syncthreads();
            stageHalf((const ull*)(hbufA + (size_t)((t - 1) & 1) * (16 * H_Q)
                                   + (size_t)hf * BH * H_Q), Ht, tid);
        }
        __syncthreads();

        float ohA[3];
        hpart(Ht, wh, kg, c7, ohA);
        float hxA = Ht[c7 * ROW_STR + (jg >> 3) * CH_STR + (jg & 7)];
        float rgA = fsig(oxA[0] + ohA[0] + br);
        float zgA = fsig(oxA[1] + ohA[1] + bz);
        float ngA = ftanh(oxA[2] + bin + rgA * (ohA[2] + bhn));
        float hnA = (1.f - zgA) * ngA + zgA * hxA;

        if (kg < 8) tbufA[kg * 9 + j] = hnA;   // kg == batch for kg<8
        __syncthreads();
        if (tid < 64) {                        // A-publish: stores only, NO wait
            float* dst = hbufA + (size_t)(t & 1) * (16 * H_Q)
                       + (size_t)hf * BH * H_Q;
            int b = tid >> 3, jl = tid & 7;
            __hip_atomic_store(dst + b * H_Q + s * JW + jl, tbufA[b * 9 + jl],
                               __ATOMIC_RELAXED, __HIP_MEMORY_SCOPE_AGENT);
        }

        // ======== half B (A's store/flag latency hides under this) ========
        float oxB[3];
        xpart(xbaseB + (size_t)(t - 1) * I_Q, xstr_b, wi, kg, oxB);

        if (t == 1) {
            stageHalf((const ull*)(h0 + (size_t)(gB * 16 + hf * BH) * H_Q),
                      Ht + 8 * ROW_STR, tid);
        } else {
            stageHalf((const ull*)(hbufB + (size_t)((t - 1) & 1) * (16 * H_Q)
                                   + (size_t)hf * BH * H_Q),
                      Ht + 8 * ROW_STR, tid);   // flags already checked above
        }
        __syncthreads();

        float ohB[3];
        hpart(Ht + 8 * ROW_STR, wh, kg, c7, ohB);
        float hxB = Ht[(8 + c7) * ROW_STR + (jg >> 3) * CH_STR + (jg & 7)];
        float rgB = fsig(oxB[0] + ohB[0] + br);
        float zgB = fsig(oxB[1] + ohB[1] + bz);
        float ngB = ftanh(oxB[2] + bin + rgB * (ohB[2] + bhn));
        float hnB = (1.f - zgB) * ngB + zgB * hxB;

        if (kg < 8) tbufB[kg * 9 + j] = hnB;
        __syncthreads();
        if (tid < 64) {
            float* dst = hbufB + (size_t)(t & 1) * (16 * H_Q)
                       + (size_t)hf * BH * H_Q;
            int b = tid >> 3, jl = tid & 7;
            __hip_atomic_store(dst + b * H_Q + s * JW + jl, tbufB[b * 9 + jl],
                               __ATOMIC_RELAXED, __HIP_MEMORY_SCOPE_AGENT);
            // vmcnt is per-wave: drains BOTH A and B publish stores of wave 0
            asm volatile("s_waitcnt vmcnt(0)" ::: "memory");
            if (tid == 0)
                __hip_atomic_store(pflags + s, t, __ATOMIC_RELAXED,
                                   __HIP_MEMORY_SCOPE_AGENT);
        }

        if (t == T_Q) {
            lrA = rgA; lzA = zgA; lnA = ngA; lhA = hnA;
            lrB = rgB; lzB = zgB; lnB = ngB; lhB = hnB;
        }
    }

    // ---- pair-done: all 128 WGs of this pair hit T -> no hbuf readers left;
    // epilogue overwrites only this pair's rows (incl. both scratch regions,
    // which the pair's own WGs fully cover with valid outputs).
    if (tid < 128) {
        int cnt = 0;
        while (__hip_atomic_load(flags + p * 128 + tid, __ATOMIC_RELAXED,
                                 __HIP_MEMORY_SCOPE_AGENT) < T_Q) {
            __builtin_amdgcn_s_sleep(2);
            if (++cnt > 100000000) break;   // hang guard
        }
    }
    __syncthreads();

    if (kg < 8) {
        size_t oA = (size_t)(gA * 16 + hf * BH + kg) * (4 * H_Q);
        out[oA + jg]            = lrA;
        out[oA + H_Q + jg]      = lzA;
        out[oA + 2 * H_Q + jg]  = lnA;
        out[oA + 3 * H_Q + jg]  = lhA;
        out[oA + C1 + jg]           = lrA;
        out[oA + C1 + H_Q + jg]     = lzA;
        out[oA + C1 + 2 * H_Q + jg] = lnA;
        out[oA + C1 + 3 * H_Q + jg] = lhA;
        size_t oB = (size_t)(gB * 16 + hf * BH + kg) * (4 * H_Q);
        out[oB + jg]            = lrB;
        out[oB + H_Q + jg]      = lzB;
        out[oB + 2 * H_Q + jg]  = lnB;
        out[oB + 3 * H_Q + jg]  = lhB;
        out[oB + C1 + jg]           = lrB;
        out[oB + C1 + H_Q + jg]     = lzB;
        out[oB + C1 + 2 * H_Q + jg] = lnB;
        out[oB + C1 + 3 * H_Q + jg] = lhB;
    }
}

extern "C" void kernel_launch(void* const* d_in, const int* in_sizes, int n_in,
                              void* d_out, int out_size, void* d_ws, size_t ws_size,
                              hipStream_t stream) {
    const float* x   = (const float*)d_in[0];
    const float* h0  = (const float*)d_in[1];
    const float* Wih = (const float*)d_in[2];
    const float* bih = (const float*)d_in[3];
    const float* Whh = (const float*)d_in[4];
    const float* bhh = (const float*)d_in[5];
    float* outp  = (float*)d_out;
    int*   flags = (int*)d_ws;   // NWG per-WG step flags (2 KB)

    (void)in_sizes; (void)n_in; (void)ws_size; (void)out_size;

    // zero the per-WG flags every launch (stream-ordered, capture-safe)
    hipMemsetAsync(d_ws, 0, NWG * sizeof(int), stream);

    gru_scan_kernel<<<dim3(NWG), dim3(NTHR), LDS_BYTES, stream>>>(
        x, h0, Wih, bih, Whh, bhh, outp, flags);
}